// Round 11
// baseline (13862.456 us; speedup 1.0000x reference)
//
#include <hip/hip_runtime.h>
#include <hip/hip_bf16.h>
#include <math.h>

#define B_ 128
#define S_ 1024
#define H_ 512
#define E_ 512
#define T_ 64
#define L_ 128
#define G4H 2048  // 4*H
#define NB 256    // persistent blocks
#define NT 512    // threads per block

typedef __attribute__((ext_vector_type(8))) short bf16x8;
typedef __attribute__((ext_vector_type(4))) float f32x4;

__device__ inline float sigmoidf_(float x) { return 1.f / (1.f + expf(-x)); }
__device__ inline float fast_tanhf_(float x) {
    float e = __expf(2.f * x);
    return 1.f - 2.f / (e + 1.f);
}
__device__ inline unsigned f2bf1(float f) {
    unsigned u = __float_as_uint(f);
    return (u + 0x7fffu + ((u >> 16) & 1u)) >> 16;
}

// Software grid barrier: monotonic counter, agent-scope atomics, bounded spin.
__device__ inline void gbar(unsigned* cnt, unsigned target) {
    __syncthreads();
    if (threadIdx.x == 0) {
        __threadfence();   // release: writeback local XCD L2
        __hip_atomic_fetch_add(cnt, 1u, __ATOMIC_RELAXED, __HIP_MEMORY_SCOPE_AGENT);
        unsigned it = 0;
        while (__hip_atomic_load(cnt, __ATOMIC_RELAXED, __HIP_MEMORY_SCOPE_AGENT) < target) {
            __builtin_amdgcn_s_sleep(2);
            if (++it > (1u << 26)) break;   // failsafe: fail, never hang
        }
        __threadfence();   // acquire: invalidate caches
    }
    __syncthreads();
}

// ---------------------------------------------------------------------------
// fp32-accurate GEMM via bf16 split MFMA (Markidis 3-product), validated R4-R6.
// ---------------------------------------------------------------------------
#define LDP 40
__global__ __launch_bounds__(256) void gemm_split(
    const float* __restrict__ A, int lda,
    const float* __restrict__ W, int ldw,
    const float* __restrict__ bias,
    const float* __restrict__ Cinit, int ldci,
    float* __restrict__ C, int ldc,
    int K, int act, int perm)
{
    __shared__ unsigned short Ah[128 * LDP];
    __shared__ unsigned short Al[128 * LDP];
    __shared__ unsigned short Bh[128 * LDP];
    __shared__ unsigned short Bl[128 * LDP];
    const int n0 = blockIdx.x * 128;
    const int m0 = blockIdx.y * 128;
    const int t = threadIdx.x;
    const int lane = t & 63, wv = t >> 6;
    const int wr = wv >> 1, wc = wv & 1;
    const int row = t >> 1, koff = (t & 1) * 16;

    f32x4 acc[4][4] = {};

    float av[16], wvv[16];
    {
        const float* ap = A + (size_t)(m0 + row) * lda + koff;
        const float* wp = W + (size_t)(n0 + row) * ldw + koff;
#pragma unroll
        for (int q = 0; q < 4; ++q) {
            *reinterpret_cast<float4*>(&av[q * 4]) = *reinterpret_cast<const float4*>(ap + q * 4);
            *reinterpret_cast<float4*>(&wvv[q * 4]) = *reinterpret_cast<const float4*>(wp + q * 4);
        }
    }

    for (int kt = 0; kt < K; kt += 32) {
        unsigned short ah[16], al[16], bh[16], bl[16];
#pragma unroll
        for (int e = 0; e < 16; ++e) {
            unsigned ha = f2bf1(av[e]);
            float hf = __uint_as_float(ha << 16);
            ah[e] = (unsigned short)ha;
            al[e] = (unsigned short)f2bf1(av[e] - hf);
            unsigned hw = f2bf1(wvv[e]);
            float hwf = __uint_as_float(hw << 16);
            bh[e] = (unsigned short)hw;
            bl[e] = (unsigned short)f2bf1(wvv[e] - hwf);
        }
        __syncthreads();
        *reinterpret_cast<uint4*>(&Ah[row * LDP + koff])     = *reinterpret_cast<uint4*>(&ah[0]);
        *reinterpret_cast<uint4*>(&Ah[row * LDP + koff + 8]) = *reinterpret_cast<uint4*>(&ah[8]);
        *reinterpret_cast<uint4*>(&Al[row * LDP + koff])     = *reinterpret_cast<uint4*>(&al[0]);
        *reinterpret_cast<uint4*>(&Al[row * LDP + koff + 8]) = *reinterpret_cast<uint4*>(&al[8]);
        *reinterpret_cast<uint4*>(&Bh[row * LDP + koff])     = *reinterpret_cast<uint4*>(&bh[0]);
        *reinterpret_cast<uint4*>(&Bh[row * LDP + koff + 8]) = *reinterpret_cast<uint4*>(&bh[8]);
        *reinterpret_cast<uint4*>(&Bl[row * LDP + koff])     = *reinterpret_cast<uint4*>(&bl[0]);
        *reinterpret_cast<uint4*>(&Bl[row * LDP + koff + 8]) = *reinterpret_cast<uint4*>(&bl[8]);
        __syncthreads();

        if (kt + 32 < K) {
            const float* ap = A + (size_t)(m0 + row) * lda + kt + 32 + koff;
            const float* wp = W + (size_t)(n0 + row) * ldw + kt + 32 + koff;
#pragma unroll
            for (int q = 0; q < 4; ++q) {
                *reinterpret_cast<float4*>(&av[q * 4]) = *reinterpret_cast<const float4*>(ap + q * 4);
                *reinterpret_cast<float4*>(&wvv[q * 4]) = *reinterpret_cast<const float4*>(wp + q * 4);
            }
        }

        bf16x8 fah[4], fal[4], fbh[4], fbl[4];
        const int kq = (lane >> 4) * 8;
#pragma unroll
        for (int i = 0; i < 4; ++i) {
            const int ar = wr * 64 + i * 16 + (lane & 15);
            const int br = wc * 64 + i * 16 + (lane & 15);
            fah[i] = *reinterpret_cast<const bf16x8*>(&Ah[ar * LDP + kq]);
            fal[i] = *reinterpret_cast<const bf16x8*>(&Al[ar * LDP + kq]);
            fbh[i] = *reinterpret_cast<const bf16x8*>(&Bh[br * LDP + kq]);
            fbl[i] = *reinterpret_cast<const bf16x8*>(&Bl[br * LDP + kq]);
        }
#pragma unroll
        for (int i = 0; i < 4; ++i)
#pragma unroll
            for (int j = 0; j < 4; ++j) {
                acc[i][j] = __builtin_amdgcn_mfma_f32_16x16x32_bf16(fah[i], fbh[j], acc[i][j], 0, 0, 0);
                acc[i][j] = __builtin_amdgcn_mfma_f32_16x16x32_bf16(fal[i], fbh[j], acc[i][j], 0, 0, 0);
                acc[i][j] = __builtin_amdgcn_mfma_f32_16x16x32_bf16(fah[i], fbl[j], acc[i][j], 0, 0, 0);
            }
    }

#pragma unroll
    for (int i = 0; i < 4; ++i)
#pragma unroll
        for (int j = 0; j < 4; ++j) {
            const int n = n0 + wc * 64 + j * 16 + (lane & 15);
            const float bs = bias ? bias[n] : 0.f;
#pragma unroll
            for (int r = 0; r < 4; ++r) {
                const int m = m0 + wr * 64 + i * 16 + (lane >> 4) * 4 + r;
                float v = acc[i][j][r] + bs;
                if (Cinit) v += Cinit[(size_t)m * ldci + n];
                if (act == 1) v = tanhf(v);
                size_t crow;
                if (perm) { int bb = m & 127, tt = m >> 7; crow = ((size_t)bb * T_ + tt) * ldc; }
                else crow = (size_t)m * ldc;
                C[crow + n] = v;
            }
        }
}

// ---------------------------------------------------------------------------
__global__ __launch_bounds__(128) void k_perm(
    const float* __restrict__ W_ih, const float* __restrict__ W_hh,
    const float* __restrict__ b_ih, const float* __restrict__ b_hh,
    float* __restrict__ Wip, float* __restrict__ Whp, float* __restrict__ bp)
{
    int rp = blockIdx.x;
    int h = rp >> 2, g = rp & 3;
    int src = g * 512 + h;
    int t = threadIdx.x;
    const float4* si = reinterpret_cast<const float4*>(W_ih + (size_t)src * 512);
    const float4* sh = reinterpret_cast<const float4*>(W_hh + (size_t)src * 512);
    float4* di = reinterpret_cast<float4*>(Wip + (size_t)rp * 512);
    float4* dh = reinterpret_cast<float4*>(Whp + (size_t)rp * 512);
    di[t] = si[t];
    dh[t] = sh[t];
    if (t == 0) bp[rp] = b_ih[src] + b_hh[src];
}

__global__ void k_embed(const float* __restrict__ dec_in, const int* __restrict__ labels,
                        const float* __restrict__ emb, float* __restrict__ X)
{
    size_t total = (size_t)T_ * B_ * E_;
    for (size_t i = (size_t)blockIdx.x * blockDim.x + threadIdx.x; i < total;
         i += (size_t)gridDim.x * blockDim.x) {
        int e = (int)(i % E_);
        int b = (int)((i / E_) % B_);
        int t = (int)(i / ((size_t)E_ * B_));
        float v;
        if (t == 0) v = dec_in[b * E_ + e];
        else {
            int lab = labels[b * T_ + (t - 1)];
            v = emb[(size_t)lab * E_ + e];
        }
        X[i] = v;
    }
}

__global__ void k_init(const float* __restrict__ h0, const float* __restrict__ c0,
                       float* __restrict__ hbuf, float* __restrict__ cbuf,
                       unsigned* __restrict__ cnt)
{
    int i = blockIdx.x * blockDim.x + threadIdx.x;
    hbuf[i] = h0[i];
    cbuf[i] = c0[i];
    if (i == 0) cnt[0] = 0u;
}

// ---------------------------------------------------------------------------
// Persistent mega-kernel: 256 blocks x 512 thr, software grid barrier.
// Phase A: gates+LSTM (128 blocks, 32m x 64n tiles, K=512)
// Phase B: Pa = hlstm @ W_ain^T (256 blocks, split-K 8, Kc=64)
// Phase C: attention (256 blocks = (b, half), 8 waves x 64 s, 4-deep prefetch)
// Phase D: hidden = tanh([weighted|hlstm] @ W_ho^T + b) (32 blocks, K=1024)
// ---------------------------------------------------------------------------
__global__ __launch_bounds__(NT, 2) void k_loop(
    const float* __restrict__ Whp, const float* __restrict__ xproj,
    const float* __restrict__ W_ain, const float* __restrict__ b_ain,
    const float* __restrict__ Vv, const float* __restrict__ W_ho,
    const float* __restrict__ b_ho, const float* __restrict__ ctx,
    float* __restrict__ cbuf, float* __restrict__ hbuf, float* __restrict__ hlstm,
    float* __restrict__ Pa, float* __restrict__ pm, float* __restrict__ pl,
    float* __restrict__ pw, float* __restrict__ hist,
    float* __restrict__ out_hf, float* __restrict__ out_cf,
    unsigned* __restrict__ cnt)
{
    const int bid = blockIdx.x;
    const int t0 = threadIdx.x;

    __shared__ float shbuf[4624];
    float (*As)[32] = reinterpret_cast<float(*)[32]>(shbuf);          // 16x32
    float (*Ws)[64] = reinterpret_cast<float(*)[64]>(shbuf + 512);    // 16x64
    float (*eql)[2] = reinterpret_cast<float(*)[2]>(shbuf + 1536);    // 32x2
    float* inp = shbuf;            // 512 (phase C)
    float* wl  = shbuf + 512;      // 4096 (phase C)
    float* ml  = shbuf + 4608;
    float* ll  = shbuf + 4616;

    const int ty = t0 >> 4;              // 0..31 m-row
    const int tx = t0 & 15;              // 4-col group
    const int alr = t0 & 31, alk = t0 >> 5;        // A staging 32r x 16k
    const int wlr = t0 & 63, wk2 = (t0 >> 6) * 2;  // W staging 64r x 8 k-pairs
    const int lane = t0 & 63, wv = t0 >> 6;

    unsigned ep = 0;

    for (int t = 0; t < T_; ++t) {
        // ===== Phase A: gates + LSTM (blocks 0..127) =====
        if (bid < 128) {
            const int m0 = (bid >> 5) * 32;
            const int n0 = (bid & 31) * 64;
            float acc[4] = {};
            float pa = hbuf[(size_t)(m0 + alr) * 512 + alk];
            float2 pv = *reinterpret_cast<const float2*>(Whp + (size_t)(n0 + wlr) * 512 + wk2);
            for (int k0 = 0; k0 < 512; k0 += 16) {
                __syncthreads();
                As[alk][alr] = pa;
                Ws[wk2][wlr] = pv.x; Ws[wk2 + 1][wlr] = pv.y;
                __syncthreads();
                if (k0 + 16 < 512) {
                    pa = hbuf[(size_t)(m0 + alr) * 512 + k0 + 16 + alk];
                    pv = *reinterpret_cast<const float2*>(Whp + (size_t)(n0 + wlr) * 512 + k0 + 16 + wk2);
                }
#pragma unroll
                for (int kk = 0; kk < 16; ++kk) {
                    float a = As[kk][ty];
#pragma unroll
                    for (int j = 0; j < 4; ++j) acc[j] = fmaf(a, Ws[kk][tx * 4 + j], acc[j]);
                }
            }
            const int h = (n0 >> 2) + tx;
            const int b = m0 + ty;
            float4 xp = *reinterpret_cast<const float4*>(xproj + (size_t)t * B_ * G4H + (size_t)b * G4H + n0 + tx * 4);
            float ig = sigmoidf_(acc[0] + xp.x);
            float fg = sigmoidf_(acc[1] + xp.y);
            float gg = tanhf(acc[2] + xp.z);
            float og = sigmoidf_(acc[3] + xp.w);
            float c = fg * cbuf[(size_t)b * 512 + h] + ig * gg;
            cbuf[(size_t)b * 512 + h] = c;
            hlstm[(size_t)b * 512 + h] = og * tanhf(c);
            if (t == T_ - 1) out_cf[(size_t)b * 512 + h] = c;
        }
        gbar(cnt, ++ep * NB);

        // ===== Phase B: Pa = hlstm @ W_ain^T (all 256, split-K 8) =====
        {
            const int ks = bid >> 5;
            const int m0 = ((bid & 31) >> 3) * 32;
            const int n0 = (bid & 7) * 64;
            const int kb = ks * 64;
            float acc[4] = {};
            float pa = hlstm[(size_t)(m0 + alr) * 512 + kb + alk];
            float2 pv = *reinterpret_cast<const float2*>(W_ain + (size_t)(n0 + wlr) * 512 + kb + wk2);
            for (int k0 = 0; k0 < 64; k0 += 16) {
                __syncthreads();
                As[alk][alr] = pa;
                Ws[wk2][wlr] = pv.x; Ws[wk2 + 1][wlr] = pv.y;
                __syncthreads();
                if (k0 + 16 < 64) {
                    pa = hlstm[(size_t)(m0 + alr) * 512 + kb + k0 + 16 + alk];
                    pv = *reinterpret_cast<const float2*>(W_ain + (size_t)(n0 + wlr) * 512 + kb + k0 + 16 + wk2);
                }
#pragma unroll
                for (int kk = 0; kk < 16; ++kk) {
                    float a = As[kk][ty];
#pragma unroll
                    for (int j = 0; j < 4; ++j) acc[j] = fmaf(a, Ws[kk][tx * 4 + j], acc[j]);
                }
            }
#pragma unroll
            for (int j = 0; j < 4; ++j)
                Pa[((size_t)ks * 128 + m0 + ty) * 512 + n0 + tx * 4 + j] = acc[j];
        }
        gbar(cnt, ++ep * NB);

        // ===== Phase C: attention (all 256 blocks: b, half) =====
        {
            const int b = bid >> 1, half = bid & 1;
            float s = b_ain[t0];
#pragma unroll
            for (int ks = 0; ks < 8; ++ks) s += Pa[((size_t)ks * 128 + b) * 512 + t0];
            inp[t0] = s;
            __syncthreads();
            float inpr[8], vr[8];
            {
                const float4* v4 = reinterpret_cast<const float4*>(Vv) + lane * 2;
                *(float4*)&vr[0] = v4[0]; *(float4*)&vr[4] = v4[1];
#pragma unroll
                for (int k = 0; k < 8; ++k) inpr[k] = inp[lane * 8 + k];
            }
            const float* sp = ctx + ((size_t)b * S_ + half * 512 + wv * 64) * 512 + lane * 8;

            float m = -INFINITY, l = 0.f, w[8] = {};
            float4 p0[4], p1[4];
#pragma unroll
            for (int j = 0; j < 4; ++j) {
                p0[j] = *reinterpret_cast<const float4*>(sp + (size_t)j * 512);
                p1[j] = *reinterpret_cast<const float4*>(sp + (size_t)j * 512 + 4);
            }
            for (int so = 0; so < 64; so += 4) {
                const bool pf = (so + 4 < 64);
#pragma unroll
                for (int j = 0; j < 4; ++j) {
                    float c8[8];
                    *(float4*)&c8[0] = p0[j]; *(float4*)&c8[4] = p1[j];
                    if (pf) {
                        p0[j] = *reinterpret_cast<const float4*>(sp + (size_t)(so + 4 + j) * 512);
                        p1[j] = *reinterpret_cast<const float4*>(sp + (size_t)(so + 4 + j) * 512 + 4);
                    }
                    float tt = 0.f;
#pragma unroll
                    for (int k = 0; k < 8; ++k) tt = fmaf(fast_tanhf_(inpr[k] + c8[k]), vr[k], tt);
#pragma unroll
                    for (int off = 32; off > 0; off >>= 1) tt += __shfl_xor(tt, off);
                    float mn = fmaxf(m, tt);
                    float sc = __expf(m - mn);
                    float p  = __expf(tt - mn);
                    l = l * sc + p;
#pragma unroll
                    for (int k = 0; k < 8; ++k) w[k] = w[k] * sc + p * c8[k];
                    m = mn;
                }
            }
#pragma unroll
            for (int k = 0; k < 8; ++k) wl[wv * 512 + lane * 8 + k] = w[k];
            if (lane == 0) { ml[wv] = m; ll[wv] = l; }
            __syncthreads();
            float M = ml[0];
#pragma unroll
            for (int u = 1; u < 8; ++u) M = fmaxf(M, ml[u]);
            float lt = 0.f, wt = 0.f;
#pragma unroll
            for (int u = 0; u < 8; ++u) {
                float e = __expf(ml[u] - M);
                lt += e * ll[u];
                wt += e * wl[u * 512 + t0];
            }
            if (t0 == 0) { pm[bid] = M; pl[bid] = lt; }
            pw[(size_t)bid * 512 + t0] = wt;
        }
        gbar(cnt, ++ep * NB);

        // ===== Phase D: hidden (blocks 0..31) =====
        if (bid < 32) {
            const int m0 = (bid >> 3) * 32;
            const int nt = bid & 7;
            const int n0 = nt * 64;
            if (t0 < 32) {
                const int row = m0 + t0;
                float q0 = pm[row * 2], q1 = pm[row * 2 + 1];
                float M = fmaxf(q0, q1);
                float e0 = __expf(q0 - M), e1 = __expf(q1 - M);
                float Lt = e0 * pl[row * 2] + e1 * pl[row * 2 + 1];
                float inv = 1.f / Lt;
                eql[t0][0] = e0 * inv; eql[t0][1] = e1 * inv;
            }
            __syncthreads();
            float* hist_t = hist + (size_t)t * B_ * 1024;
            float acc[4] = {};
            auto ld_a = [&](int k0) -> float {
                const int row = m0 + alr;
                const int k = k0 + alk;
                if (k0 < 512) {
                    float v = eql[alr][0] * pw[((size_t)row * 2) * 512 + k]
                            + eql[alr][1] * pw[((size_t)row * 2 + 1) * 512 + k];
                    if (nt == 0) hist_t[(size_t)row * 1024 + 512 + k] = v;
                    return v;
                }
                return hlstm[(size_t)row * 512 + k - 512];
            };
            float pa = ld_a(0);
            float2 pv = *reinterpret_cast<const float2*>(W_ho + (size_t)(n0 + wlr) * 1024 + wk2);
            for (int k0 = 0; k0 < 1024; k0 += 16) {
                __syncthreads();
                As[alk][alr] = pa;
                Ws[wk2][wlr] = pv.x; Ws[wk2 + 1][wlr] = pv.y;
                __syncthreads();
                if (k0 + 16 < 1024) {
                    pa = ld_a(k0 + 16);
                    pv = *reinterpret_cast<const float2*>(W_ho + (size_t)(n0 + wlr) * 1024 + k0 + 16 + wk2);
                }
#pragma unroll
                for (int kk = 0; kk < 16; ++kk) {
                    float a = As[kk][ty];
#pragma unroll
                    for (int j = 0; j < 4; ++j) acc[j] = fmaf(a, Ws[kk][tx * 4 + j], acc[j]);
                }
            }
            const int b = m0 + ty;
#pragma unroll
            for (int j = 0; j < 4; ++j) {
                const int n = n0 + tx * 4 + j;
                float v = tanhf(acc[j] + b_ho[n]);
                hbuf[(size_t)b * 512 + n] = v;
                hist_t[(size_t)b * 1024 + n] = v;
                if (t == T_ - 1) out_hf[(size_t)b * 512 + n] = v;
            }
        }
        gbar(cnt, ++ep * NB);
    }
}

__global__ __launch_bounds__(128) void k_argmax(const float* __restrict__ outp,
                                                float* __restrict__ preds)
{
    int row = blockIdx.x;
    int tid = threadIdx.x;
    float v = outp[(size_t)row * L_ + tid];
    int idx = tid;
#pragma unroll
    for (int off = 32; off > 0; off >>= 1) {
        float ov = __shfl_xor(v, off);
        int oi = __shfl_xor(idx, off);
        if (ov > v || (ov == v && oi < idx)) { v = ov; idx = oi; }
    }
    __shared__ float sv[2];
    __shared__ int si[2];
    if ((tid & 63) == 0) { sv[tid >> 6] = v; si[tid >> 6] = idx; }
    __syncthreads();
    if (tid == 0) {
        float v0 = sv[0], v1 = sv[1];
        int i0 = si[0], i1 = si[1];
        int r = (v1 > v0 || (v1 == v0 && i1 < i0)) ? i1 : i0;
        preds[row] = (float)r;
    }
}

// ---------------------------------------------------------------------------
extern "C" void kernel_launch(void* const* d_in, const int* in_sizes, int n_in,
                              void* d_out, int out_size, void* d_ws, size_t ws_size,
                              hipStream_t stream)
{
    const float* dec_in  = (const float*)d_in[2];
    const float* h0      = (const float*)d_in[3];
    const float* c0      = (const float*)d_in[4];
    const float* context = (const float*)d_in[5];
    const int*   labels  = (const int*)d_in[6];
    const float* emb     = (const float*)d_in[8];
    const float* W_ih    = (const float*)d_in[9];
    const float* b_ih    = (const float*)d_in[10];
    const float* W_hh    = (const float*)d_in[11];
    const float* b_hh    = (const float*)d_in[12];
    const float* W_ho    = (const float*)d_in[13];
    const float* b_ho    = (const float*)d_in[14];
    const float* W_ain   = (const float*)d_in[15];
    const float* b_ain   = (const float*)d_in[16];
    const float* W_actx  = (const float*)d_in[17];
    const float* b_actx  = (const float*)d_in[18];
    const float* Vv      = (const float*)d_in[19];
    const float* W_out   = (const float*)d_in[20];
    const float* b_out   = (const float*)d_in[21];

    float* ws = (float*)d_ws;
    unsigned* cnt = (unsigned*)ws; ws += 64;                 // barrier counter line
    float* X     = ws; ws += (size_t)T_ * B_ * E_;
    float* xproj = ws; ws += (size_t)T_ * B_ * G4H;
    float* xout  = ws; ws += (size_t)T_ * B_ * L_;
    float* ctx   = ws; ws += (size_t)B_ * S_ * H_;           // fp32-exact (R8 verdict)
    float* hist  = ws; ws += (size_t)T_ * B_ * 1024;
    float* Wip   = ws; ws += (size_t)G4H * 512;
    float* Whp   = ws; ws += (size_t)G4H * 512;
    float* bp    = ws; ws += G4H;
    float* Pa    = ws; ws += (size_t)8 * B_ * H_;
    float* cbuf  = ws; ws += (size_t)B_ * H_;
    float* hbuf  = ws; ws += (size_t)B_ * H_;
    float* hlstm = ws; ws += (size_t)B_ * H_;
    float* pm    = ws; ws += (size_t)B_ * 2;
    float* pl    = ws; ws += (size_t)B_ * 2;
    float* pw    = ws; ws += (size_t)B_ * 2 * 512;

    float* out_logits = (float*)d_out;
    float* out_preds  = out_logits + (size_t)B_ * T_ * L_;
    float* out_hf     = out_preds + (size_t)B_ * T_;
    float* out_cf     = out_hf + (size_t)B_ * H_;

    // ---- precompute ----
    k_embed<<<2048, 256, 0, stream>>>(dec_in, labels, emb, X);
    k_init<<<256, 256, 0, stream>>>(h0, c0, hbuf, cbuf, cnt);
    k_perm<<<G4H, 128, 0, stream>>>(W_ih, W_hh, b_ih, b_hh, Wip, Whp, bp);
    gemm_split<<<dim3(16, 64), 256, 0, stream>>>(X, E_, Wip, E_, bp, nullptr, 0,
                                                 xproj, G4H, E_, 0, 0);
    gemm_split<<<dim3(1, 64), 256, 0, stream>>>(X, E_, W_out + 1024, 1536, b_out, nullptr, 0,
                                                xout, L_, E_, 0, 0);
    gemm_split<<<dim3(4, 1024), 256, 0, stream>>>(context, H_, W_actx, H_, b_actx, nullptr, 0,
                                                  ctx, H_, H_, 0, 0);

    // ---- sequential decode: persistent kernel, software grid barrier ----
    k_loop<<<NB, NT, 0, stream>>>(Whp, xproj, W_ain, b_ain, Vv, W_ho, b_ho, ctx,
                                  cbuf, hbuf, hlstm, Pa, pm, pl, pw, hist,
                                  out_hf, out_cf, cnt);

    // ---- post loop: deferred logits GEMM + argmax ----
    gemm_split<<<dim3(1, 64), 256, 0, stream>>>(hist, 1024, W_out, 1536, nullptr,
                                                xout, L_, out_logits, L_, 1024, 0, 1);
    k_argmax<<<B_ * T_, 128, 0, stream>>>(out_logits, out_preds);
}